// Round 6
// baseline (483.449 us; speedup 1.0000x reference)
//
#include <hip/hip_runtime.h>
#include <hip/hip_bf16.h>
#include <math.h>

// GanDTI forward. B=4096, N_ATOMS=50, FEAT=40, GNN_DEPTH=3, MLP_DEPTH=2.
//
// k_heavy (UNCHANGED from round 5): 5120 blocks x 256 threads.
//   blocks [0,1024):   A69 [B*1001 rows][30] streaming dot with W1 -> ws_a69
//   blocks [1024,5120): GNN, one sample/block; LDS = comp+h only; Wg,A from global.
// k_tail (NEW): 256 blocks x 256 threads, 16 samples/block.
//   Phase A: a256 = a69 @ W2 as tiled GEMM — a69T chunk [128][16] in LDS
//            (broadcast b128 reads), W2 b128 from global/L2, thread = 4sx4c.
//   Then p256 in registers, p40, attention, 2-layer MLP (round-4 code).

#define BATCH 4096
#define SC 44              // comp/h row stride (floats)
#define R_TOT 4100096      // 4096*1001
#define T_STR 262144       // 1024*256 streaming threads

__global__ __launch_bounds__(256) void k_heavy(
    const int* __restrict__ atoms, const float* __restrict__ A,
    const float* __restrict__ A69, const float* __restrict__ emb,
    const float* __restrict__ Wg, const float* __restrict__ bg,
    const float* __restrict__ W1, const float* __restrict__ b1,
    float* __restrict__ ws_cv, float* __restrict__ ws_a69)
{
    __shared__ float sm[4400];   // comp [50][44] + h [50][44]
    const int tid = threadIdx.x;
    const int blk = blockIdx.x;

    if (blk < 1024) {
        // ================= A69 row stream: a69[r] = A69[r,:] . W1 + b1 =================
        float w1r[30];
        #pragma unroll
        for (int k = 0; k < 15; ++k) {
            float2 t = ((const float2*)W1)[k];
            w1r[2 * k] = t.x; w1r[2 * k + 1] = t.y;
        }
        const float b1v = b1[0];
        const int t0 = (blk << 8) + tid;
        for (size_t r = t0; r < (size_t)R_TOT; r += T_STR) {
            const float2* p = (const float2*)(A69 + r * 30);
            float v = b1v;
            #pragma unroll
            for (int k = 0; k < 15; ++k) {
                float2 q = p[k];
                v = fmaf(q.x, w1r[2 * k], v);
                v = fmaf(q.y, w1r[2 * k + 1], v);
            }
            ws_a69[r] = v;
        }
    } else {
        // ================= GNN: one sample per block =================
        const int b = blk - 1024;
        float* comp = sm;          // [50][SC]
        float* h_s  = sm + 2200;   // [50][SC]

        for (int idx = tid; idx < 500; idx += 256) {
            const int n = idx / 10, f4 = idx - n * 10;
            const int row = atoms[b * 50 + n];
            *(float4*)(comp + n * SC + f4 * 4) = *(const float4*)(emb + row * 40 + f4 * 4);
        }
        __syncthreads();

        float res_sum = 0.f;
        if (tid < 40) {
            for (int n = 0; n < 50; ++n) res_sum += comp[n * SC + tid];
        }

        const int np = tid / 10, fg = tid - np * 10;
        const int n0 = np * 2, f0 = fg * 4;
        const bool act = (tid < 250);
        const float* Arow0 = A + (size_t)b * 2500 + n0 * 50;

        for (int l = 0; l < 3; ++l) {
            const float* wgl = Wg + l * 1600;
            if (act) {
                float bgv[4];
                *(float4*)bgv = *(const float4*)(bg + l * 40 + f0);
                float acc0[4] = {bgv[0], bgv[1], bgv[2], bgv[3]};
                float acc1[4] = {bgv[0], bgv[1], bgv[2], bgv[3]};
                #pragma unroll
                for (int j4 = 0; j4 < 10; ++j4) {
                    float c0a[4], c1a[4];
                    *(float4*)c0a = *(float4*)(comp + n0 * SC + j4 * 4);
                    *(float4*)c1a = *(float4*)(comp + n0 * SC + SC + j4 * 4);
                    #pragma unroll
                    for (int u = 0; u < 4; ++u) {
                        float wv[4];
                        *(float4*)wv = *(const float4*)(wgl + (j4 * 4 + u) * 40 + f0);
                        #pragma unroll
                        for (int q = 0; q < 4; ++q) {
                            acc0[q] = fmaf(c0a[u], wv[q], acc0[q]);
                            acc1[q] = fmaf(c1a[u], wv[q], acc1[q]);
                        }
                    }
                }
                float h0[4], h1[4];
                #pragma unroll
                for (int q = 0; q < 4; ++q) {
                    h0[q] = acc0[q] > 0.f ? acc0[q] : 0.01f * acc0[q];
                    h1[q] = acc1[q] > 0.f ? acc1[q] : 0.01f * acc1[q];
                }
                *(float4*)(h_s + n0 * SC + f0) = *(float4*)h0;
                *(float4*)(h_s + n0 * SC + SC + f0) = *(float4*)h1;
            }
            __syncthreads();
            if (act) {
                float acc0[4] = {0, 0, 0, 0}, acc1[4] = {0, 0, 0, 0};
                #pragma unroll
                for (int m4 = 0; m4 < 12; ++m4) {
                    float a0a[4], a1a[4];
                    *(float4*)a0a       = *(const float4*)(Arow0 + m4 * 4);
                    *(float2*)a1a       = *(const float2*)(Arow0 + 50 + m4 * 4);
                    *(float2*)(a1a + 2) = *(const float2*)(Arow0 + 50 + m4 * 4 + 2);
                    #pragma unroll
                    for (int u = 0; u < 4; ++u) {
                        float hv[4];
                        *(float4*)hv = *(float4*)(h_s + (m4 * 4 + u) * SC + f0);
                        #pragma unroll
                        for (int q = 0; q < 4; ++q) {
                            acc0[q] = fmaf(a0a[u], hv[q], acc0[q]);
                            acc1[q] = fmaf(a1a[u], hv[q], acc1[q]);
                        }
                    }
                }
                {
                    float2 at0 = *(const float2*)(Arow0 + 48);
                    float2 at1 = *(const float2*)(Arow0 + 50 + 48);
                    float h48[4], h49[4];
                    *(float4*)h48 = *(float4*)(h_s + 48 * SC + f0);
                    *(float4*)h49 = *(float4*)(h_s + 49 * SC + f0);
                    #pragma unroll
                    for (int q = 0; q < 4; ++q) {
                        acc0[q] = fmaf(at0.x, h48[q], acc0[q]);
                        acc0[q] = fmaf(at0.y, h49[q], acc0[q]);
                        acc1[q] = fmaf(at1.x, h48[q], acc1[q]);
                        acc1[q] = fmaf(at1.y, h49[q], acc1[q]);
                    }
                }
                float c0a[4], c1a[4];
                *(float4*)c0a = *(float4*)(comp + n0 * SC + f0);
                *(float4*)c1a = *(float4*)(comp + n0 * SC + SC + f0);
                #pragma unroll
                for (int q = 0; q < 4; ++q) { c0a[q] += acc0[q]; c1a[q] += acc1[q]; }
                *(float4*)(comp + n0 * SC + f0) = *(float4*)c0a;
                *(float4*)(comp + n0 * SC + SC + f0) = *(float4*)c1a;
            }
            __syncthreads();
        }
        if (tid < 40) {
            float s = res_sum;
            for (int n = 0; n < 50; ++n) s += comp[n * SC + tid];
            ws_cv[(size_t)b * 40 + tid] = s * 0.02f;
        }
    }
}

__global__ __launch_bounds__(256) void k_tail(
    const float* __restrict__ protein,
    const float* __restrict__ W2, const float* __restrict__ b2,
    const float* __restrict__ W3, const float* __restrict__ b3,
    const float* __restrict__ Wp, const float* __restrict__ bp,
    const float* __restrict__ Watt, const float* __restrict__ batt,
    const float* __restrict__ Wm, const float* __restrict__ bm,
    const float* __restrict__ Wo, const float* __restrict__ bo,
    const float* __restrict__ ws_cv, const float* __restrict__ ws_a69,
    float* __restrict__ out)
{
    const int G = 16, PC = 520;
    __shared__ float pc[16 * 520];     // [a256(256) | p256(256)] per sample
    __shared__ float a69T[128 * 16];   // k-chunk of a69, transposed [k][sample]
    __shared__ float p40s[16 * 40];
    __shared__ float phs[16 * 40];
    __shared__ float wts[16];
    __shared__ float cps[2][16 * 84];
    const int tid  = threadIdx.x;
    const int lane = tid & 63;
    const int wv   = tid >> 6;
    const int blk  = blockIdx.x;
    const int b0   = blk * G;
    const int c0   = lane * 4;

    // ---- Phase A: a256 = a69 @ W2 + b2, tiled GEMM ----
    // thread = 4 samples (sgroup = wv) x 4 cols (cgroup = lane)
    {
        const int sg = wv;                 // samples [sg*4, sg*4+4)
        float acc[4][4];
        #pragma unroll
        for (int s = 0; s < 4; ++s)
            #pragma unroll
            for (int c = 0; c < 4; ++c) acc[s][c] = 0.f;

        for (int ch = 0; ch < 8; ++ch) {
            const int k0 = ch * 128;
            const int nr = (ch == 7) ? 105 : 128;
            if (ch) __syncthreads();       // protect a69T reuse
            #pragma unroll
            for (int r = 0; r < 8; ++r) {
                const int idx = tid + r * 256;       // 2048 = 16 samples x 128 k
                const int s = idx >> 7, k = idx & 127;
                const float v = (k < nr)
                    ? ws_a69[(size_t)(b0 + s) * 1001 + k0 + k] : 0.f;
                a69T[k * 16 + s] = v;
            }
            __syncthreads();
            for (int k = 0; k < nr; ++k) {
                float av[4];
                *(float4*)av = *(float4*)(a69T + k * 16 + sg * 4);  // broadcast b128
                float w2v[4];
                *(float4*)w2v = *(const float4*)(W2 + (size_t)(k0 + k) * 256 + c0);
                #pragma unroll
                for (int s = 0; s < 4; ++s)
                    #pragma unroll
                    for (int c = 0; c < 4; ++c)
                        acc[s][c] = fmaf(av[s], w2v[c], acc[s][c]);
            }
        }
        float b2v[4];
        *(float4*)b2v = *(const float4*)(b2 + c0);
        #pragma unroll
        for (int s = 0; s < 4; ++s) {
            const int g = sg * 4 + s;
            float o[4];
            #pragma unroll
            for (int c = 0; c < 4; ++c) o[c] = acc[s][c] + b2v[c];
            *(float4*)(pc + g * PC + c0) = *(float4*)o;
        }
    }

    // ---- p256 = protein @ W3 + b3 (registers, 4 samples per wave) ----
    {
        float acc[4][4];
        #pragma unroll
        for (int s = 0; s < 4; ++s)
            #pragma unroll
            for (int c = 0; c < 4; ++c) acc[s][c] = 0.f;
        const float* prot = protein + (size_t)(b0 + wv * 4) * 512;
        for (int j4 = 0; j4 < 128; ++j4) {
            float pv[4][4];
            #pragma unroll
            for (int s = 0; s < 4; ++s)
                *(float4*)pv[s] = *(const float4*)(prot + (size_t)s * 512 + j4 * 4);
            #pragma unroll
            for (int u = 0; u < 4; ++u) {
                float w3v[4];
                *(float4*)w3v = *(const float4*)(W3 + (size_t)(j4 * 4 + u) * 256 + c0);
                #pragma unroll
                for (int s = 0; s < 4; ++s)
                    #pragma unroll
                    for (int c = 0; c < 4; ++c)
                        acc[s][c] = fmaf(pv[s][u], w3v[c], acc[s][c]);
            }
        }
        float b3v[4];
        *(float4*)b3v = *(const float4*)(b3 + c0);
        #pragma unroll
        for (int s = 0; s < 4; ++s) {
            const int g = wv * 4 + s;
            float o[4];
            #pragma unroll
            for (int c = 0; c < 4; ++c) o[c] = acc[s][c] + b3v[c];
            *(float4*)(pc + g * PC + 256 + c0) = *(float4*)o;
        }
    }
    __syncthreads();

    // ---- p40 = pcat @ Wp + bp  (80 tasks: (f8,g), 8 cols each) ----
    if (tid < 80) {
        const int f8 = tid >> 4, g = tid & 15, fo = f8 * 8;
        float a8[8];
        #pragma unroll
        for (int c = 0; c < 8; ++c) a8[c] = bp[fo + c];
        for (int j4 = 0; j4 < 128; ++j4) {
            float pv[4];
            *(float4*)pv = *(float4*)(pc + g * PC + j4 * 4);
            #pragma unroll
            for (int u = 0; u < 4; ++u) {
                const int j = j4 * 4 + u;
                float wa[4], wb[4];
                *(float4*)wa = *(const float4*)(Wp + j * 40 + fo);
                *(float4*)wb = *(const float4*)(Wp + j * 40 + fo + 4);
                #pragma unroll
                for (int c = 0; c < 4; ++c) {
                    a8[c]     = fmaf(pv[u], wa[c], a8[c]);
                    a8[4 + c] = fmaf(pv[u], wb[c], a8[4 + c]);
                }
            }
        }
        *(float4*)(p40s + g * 40 + fo)     = *(float4*)a8;
        *(float4*)(p40s + g * 40 + fo + 4) = *(float4*)(a8 + 4);
    }
    __syncthreads();

    // ---- protein_h = relu(p40 @ Watt + batt) ----
    for (int it = tid; it < G * 40; it += 256) {
        const int g = it / 40, f = it - g * 40;
        float s = batt[f];
        #pragma unroll
        for (int j4 = 0; j4 < 10; ++j4) {
            float pv[4];
            *(float4*)pv = *(float4*)(p40s + g * 40 + j4 * 4);
            #pragma unroll
            for (int u = 0; u < 4; ++u)
                s = fmaf(pv[u], Watt[(j4 * 4 + u) * 40 + f], s);
        }
        phs[it] = s > 0.f ? s : 0.f;
    }
    __syncthreads();

    // ---- attention weight ----
    if (tid < G) {
        float m = 0.f;
        #pragma unroll
        for (int f4 = 0; f4 < 10; ++f4) {
            float cv[4], ph[4];
            *(float4*)cv = *(const float4*)(ws_cv + (size_t)(b0 + tid) * 40 + f4 * 4);
            *(float4*)ph = *(float4*)(phs + tid * 40 + f4 * 4);
            #pragma unroll
            for (int c = 0; c < 4; ++c) m = fmaf(cv[c], ph[c], m);
        }
        wts[tid] = tanhf(m);
    }
    __syncthreads();

    // ---- cp = [compound_vec | weights * protein_h] ----
    for (int it = tid; it < G * 80; it += 256) {
        const int g = it / 80, f = it - g * 80;
        const float v = (f < 40) ? ws_cv[(size_t)(b0 + g) * 40 + f]
                                 : wts[g] * phs[g * 40 + (f - 40)];
        cps[0][g * 84 + f] = v;
    }
    __syncthreads();

    // ---- MLP head ----
    int cb = 0;
    for (int l = 0; l < 2; ++l) {
        for (int it = tid; it < G * 80; it += 256) {
            const int g = it / 80, kk = it - g * 80;
            float s = bm[l * 80 + kk];
            #pragma unroll
            for (int j4 = 0; j4 < 20; ++j4) {
                float cv[4];
                *(float4*)cv = *(float4*)(cps[cb] + g * 84 + j4 * 4);
                #pragma unroll
                for (int u = 0; u < 4; ++u)
                    s = fmaf(cv[u], Wm[l * 6400 + (j4 * 4 + u) * 80 + kk], s);
            }
            cps[cb ^ 1][g * 84 + kk] = s > 0.f ? s : 0.f;
        }
        __syncthreads();
        cb ^= 1;
    }
    if (tid < G) {
        float s = bo[0];
        #pragma unroll
        for (int j4 = 0; j4 < 20; ++j4) {
            float cv[4], wo[4];
            *(float4*)cv = *(float4*)(cps[cb] + tid * 84 + j4 * 4);
            *(float4*)wo = *(const float4*)(Wo + j4 * 4);
            #pragma unroll
            for (int u = 0; u < 4; ++u) s = fmaf(cv[u], wo[u], s);
        }
        out[b0 + tid] = s;
    }
}

extern "C" void kernel_launch(void* const* d_in, const int* in_sizes, int n_in,
                              void* d_out, int out_size, void* d_ws, size_t ws_size,
                              hipStream_t stream) {
    const int*   atoms   = (const int*)d_in[0];
    const float* A       = (const float*)d_in[1];
    const float* A69     = (const float*)d_in[2];
    const float* protein = (const float*)d_in[3];
    const float* emb     = (const float*)d_in[4];
    const float* Wg      = (const float*)d_in[5];
    const float* bg      = (const float*)d_in[6];
    const float* Watt    = (const float*)d_in[7];
    const float* batt    = (const float*)d_in[8];
    const float* W1      = (const float*)d_in[9];
    const float* b1      = (const float*)d_in[10];
    const float* W2      = (const float*)d_in[11];
    const float* b2      = (const float*)d_in[12];
    const float* W3      = (const float*)d_in[13];
    const float* b3      = (const float*)d_in[14];
    const float* Wp      = (const float*)d_in[15];
    const float* bp      = (const float*)d_in[16];
    const float* Wm      = (const float*)d_in[17];
    const float* bm      = (const float*)d_in[18];
    const float* Wo      = (const float*)d_in[19];
    const float* bo      = (const float*)d_in[20];

    float* ws_cv  = (float*)d_ws;                  // [4096][40]
    float* ws_a69 = ws_cv + (size_t)BATCH * 40;    // [4096*1001]
    float* outp   = (float*)d_out;

    k_heavy<<<dim3(1024 + BATCH), dim3(256), 0, stream>>>(
        atoms, A, A69, emb, Wg, bg, W1, b1, ws_cv, ws_a69);
    k_tail<<<dim3(256), dim3(256), 0, stream>>>(
        protein, W2, b2, W3, b3, Wp, bp, Watt, batt, Wm, bm, Wo, bo,
        ws_cv, ws_a69, outp);
}

// Round 7
// 370.066 us; speedup vs baseline: 1.3064x; 1.3064x over previous
//
#include <hip/hip_runtime.h>
#include <hip/hip_bf16.h>
#include <math.h>

// GanDTI forward. B=4096, N_ATOMS=50, FEAT=40, GNN_DEPTH=3, MLP_DEPTH=2.
//
// Three kernels (separate for per-kernel rocprof attribution):
//  k_stream: 4096 blocks x 256 thr = 512 sample-groups x 8 k-chunks.
//            partial_a256[kc][sample][256] = a69_chunk @ W2_chunk, where
//            a69 = A69@W1+b1 computed on the fly (LDS-staged per 64-row half).
//  k_gnn:    4096 blocks x 64 thr (ONE WAVE per sample, no barriers).
//            5 rows x 8 cols register tile; comp/h in LDS (stride 44);
//            Wg staged to LDS per layer; A read from global (float2, 8B-aligned).
//  k_tail:   512 blocks x 256 thr, 8 samples/block. a256 = reduce partials + b2;
//            p256 in registers; p40/attention/MLP head.

#define BATCH 4096
#define SC 44   // comp/h row stride in k_gnn

// ===================== k_stream =====================
__global__ __launch_bounds__(256) void k_stream(
    const float* __restrict__ A69, const float* __restrict__ W1,
    const float* __restrict__ b1, const float* __restrict__ W2,
    float* __restrict__ ws_part)
{
    __shared__ float a69s[64 * 10];
    const int tid  = threadIdx.x;
    const int lane = tid & 63, wv = tid >> 6;
    const int kc = blockIdx.x & 7, sg = blockIdx.x >> 3;
    const int s0 = sg * 8, k0 = kc * 128;
    const int c0 = lane * 4;

    float w1r[30];
    #pragma unroll
    for (int k = 0; k < 15; ++k) {
        float2 t = ((const float2*)W1)[k];
        w1r[2 * k] = t.x; w1r[2 * k + 1] = t.y;
    }
    const float b1v = b1[0];

    float acc[2][4] = {{0.f,0.f,0.f,0.f},{0.f,0.f,0.f,0.f}};

    for (int h = 0; h < 2; ++h) {
        const int base = k0 + h * 64;
        const int nrh = (1001 - base < 64) ? (1001 - base) : 64;  // kc=7,h=1 -> 41
        if (h) __syncthreads();
        for (int idx = tid; idx < 512; idx += 256) {
            const int s = idx >> 6, rr = idx & 63;
            if (rr < nrh) {
                const float2* p = (const float2*)(A69 + ((size_t)(s0 + s) * 1001 + base + rr) * 30);
                float v = b1v;
                #pragma unroll
                for (int k = 0; k < 15; ++k) {
                    float2 q = p[k];
                    v = fmaf(q.x, w1r[2 * k], v);
                    v = fmaf(q.y, w1r[2 * k + 1], v);
                }
                a69s[rr * 10 + s] = v;
            }
        }
        __syncthreads();
        for (int k = 0; k < nrh; ++k) {
            const float a0 = a69s[k * 10 + wv * 2];       // wave-uniform broadcast
            const float a1 = a69s[k * 10 + wv * 2 + 1];
            float w2v[4];
            *(float4*)w2v = *(const float4*)(W2 + (size_t)(base + k) * 256 + c0);
            #pragma unroll
            for (int c = 0; c < 4; ++c) {
                acc[0][c] = fmaf(a0, w2v[c], acc[0][c]);
                acc[1][c] = fmaf(a1, w2v[c], acc[1][c]);
            }
        }
    }
    #pragma unroll
    for (int s = 0; s < 2; ++s)
        *(float4*)(ws_part + ((size_t)kc * BATCH + s0 + wv * 2 + s) * 256 + c0) = *(float4*)acc[s];
}

// ===================== k_gnn =====================
__global__ __launch_bounds__(64, 2) void k_gnn(
    const int* __restrict__ atoms, const float* __restrict__ A,
    const float* __restrict__ emb, const float* __restrict__ Wg,
    const float* __restrict__ bg, float* __restrict__ ws_cv)
{
    __shared__ float comp[50 * SC];
    __shared__ float h_s[50 * SC];
    __shared__ float wg_s[1600];
    const int lane = threadIdx.x;
    const int b = blockIdx.x;

    // stage comp = emb[atoms] (same-wave in-order LDS: no barriers needed anywhere)
    for (int i = lane; i < 500; i += 64) {
        const int n = i / 10, f4 = i - n * 10;
        const int row = atoms[b * 50 + n];
        *(float4*)(comp + n * SC + f4 * 4) = *(const float4*)(emb + row * 40 + f4 * 4);
    }

    const int rg = lane / 5;          // 0..9 (valid for lane<50)
    const int cg = lane - rg * 5;     // 0..4
    const int n0 = rg * 5, f0 = cg * 8;
    const bool act = (lane < 50);

    // residual partial over own 5 rows
    float res8[8] = {0,0,0,0,0,0,0,0};
    if (act) {
        #pragma unroll
        for (int k = 0; k < 5; ++k) {
            float cv[8];
            *(float4*)cv       = *(float4*)(comp + (n0 + k) * SC + f0);
            *(float4*)(cv + 4) = *(float4*)(comp + (n0 + k) * SC + f0 + 4);
            #pragma unroll
            for (int c = 0; c < 8; ++c) res8[c] += cv[c];
        }
    }

    const float* Ab = A + (size_t)b * 2500;

    for (int l = 0; l < 3; ++l) {
        // stage Wg[l] (overwrite safe: prior m1 reads completed in program order)
        for (int i = lane; i < 400; i += 64)
            *(float4*)(wg_s + i * 4) = *(const float4*)(Wg + l * 1600 + i * 4);
        if (act) {
            // ---- m1: h = leaky(comp @ Wg[l] + bg[l]) ----
            float bgv[8];
            *(float4*)bgv       = *(const float4*)(bg + l * 40 + f0);
            *(float4*)(bgv + 4) = *(const float4*)(bg + l * 40 + f0 + 4);
            float acc[5][8];
            #pragma unroll
            for (int k = 0; k < 5; ++k)
                #pragma unroll
                for (int c = 0; c < 8; ++c) acc[k][c] = bgv[c];
            for (int j4 = 0; j4 < 10; ++j4) {
                float cv[5][4];
                #pragma unroll
                for (int k = 0; k < 5; ++k)
                    *(float4*)cv[k] = *(float4*)(comp + (n0 + k) * SC + j4 * 4);
                #pragma unroll
                for (int u = 0; u < 4; ++u) {
                    float w8[8];
                    *(float4*)w8       = *(float4*)(wg_s + (j4 * 4 + u) * 40 + f0);
                    *(float4*)(w8 + 4) = *(float4*)(wg_s + (j4 * 4 + u) * 40 + f0 + 4);
                    #pragma unroll
                    for (int k = 0; k < 5; ++k)
                        #pragma unroll
                        for (int c = 0; c < 8; ++c)
                            acc[k][c] = fmaf(cv[k][u], w8[c], acc[k][c]);
                }
            }
            #pragma unroll
            for (int k = 0; k < 5; ++k) {
                float hv[8];
                #pragma unroll
                for (int c = 0; c < 8; ++c) {
                    const float s = acc[k][c];
                    hv[c] = s > 0.f ? s : 0.01f * s;
                }
                *(float4*)(h_s + (n0 + k) * SC + f0)     = *(float4*)hv;
                *(float4*)(h_s + (n0 + k) * SC + f0 + 4) = *(float4*)(hv + 4);
            }
            // ---- m2: comp += A @ h (A from global, float2 = 8B-aligned) ----
            float acc2[5][8];
            #pragma unroll
            for (int k = 0; k < 5; ++k)
                #pragma unroll
                for (int c = 0; c < 8; ++c) acc2[k][c] = 0.f;
            for (int m4 = 0; m4 < 12; ++m4) {
                float af[5][4];
                #pragma unroll
                for (int k = 0; k < 5; ++k) {
                    *(float2*)af[k]       = *(const float2*)(Ab + (n0 + k) * 50 + m4 * 4);
                    *(float2*)(af[k] + 2) = *(const float2*)(Ab + (n0 + k) * 50 + m4 * 4 + 2);
                }
                #pragma unroll
                for (int u = 0; u < 4; ++u) {
                    float h8[8];
                    *(float4*)h8       = *(float4*)(h_s + (m4 * 4 + u) * SC + f0);
                    *(float4*)(h8 + 4) = *(float4*)(h_s + (m4 * 4 + u) * SC + f0 + 4);
                    #pragma unroll
                    for (int k = 0; k < 5; ++k)
                        #pragma unroll
                        for (int c = 0; c < 8; ++c)
                            acc2[k][c] = fmaf(af[k][u], h8[c], acc2[k][c]);
                }
            }
            {   // tail m = 48, 49
                float h48[8], h49[8];
                *(float4*)h48       = *(float4*)(h_s + 48 * SC + f0);
                *(float4*)(h48 + 4) = *(float4*)(h_s + 48 * SC + f0 + 4);
                *(float4*)h49       = *(float4*)(h_s + 49 * SC + f0);
                *(float4*)(h49 + 4) = *(float4*)(h_s + 49 * SC + f0 + 4);
                #pragma unroll
                for (int k = 0; k < 5; ++k) {
                    const float a48 = Ab[(n0 + k) * 50 + 48];
                    const float a49 = Ab[(n0 + k) * 50 + 49];
                    #pragma unroll
                    for (int c = 0; c < 8; ++c) {
                        acc2[k][c] = fmaf(a48, h48[c], acc2[k][c]);
                        acc2[k][c] = fmaf(a49, h49[c], acc2[k][c]);
                    }
                }
            }
            #pragma unroll
            for (int k = 0; k < 5; ++k) {
                float cv[8];
                *(float4*)cv       = *(float4*)(comp + (n0 + k) * SC + f0);
                *(float4*)(cv + 4) = *(float4*)(comp + (n0 + k) * SC + f0 + 4);
                #pragma unroll
                for (int c = 0; c < 8; ++c) cv[c] += acc2[k][c];
                *(float4*)(comp + (n0 + k) * SC + f0)     = *(float4*)cv;
                *(float4*)(comp + (n0 + k) * SC + f0 + 4) = *(float4*)(cv + 4);
            }
        }
    }

    // mean over atoms + residual: per-thread 5-row column sums -> h_s[10][40] -> reduce
    if (act) {
        float s8[8];
        #pragma unroll
        for (int c = 0; c < 8; ++c) s8[c] = res8[c];
        #pragma unroll
        for (int k = 0; k < 5; ++k) {
            float cv[8];
            *(float4*)cv       = *(float4*)(comp + (n0 + k) * SC + f0);
            *(float4*)(cv + 4) = *(float4*)(comp + (n0 + k) * SC + f0 + 4);
            #pragma unroll
            for (int c = 0; c < 8; ++c) s8[c] += cv[c];
        }
        *(float4*)(h_s + rg * 40 + f0)     = *(float4*)s8;
        *(float4*)(h_s + rg * 40 + f0 + 4) = *(float4*)(s8 + 4);
    }
    if (lane < 40) {
        float s = 0.f;
        #pragma unroll
        for (int r = 0; r < 10; ++r) s += h_s[r * 40 + lane];
        ws_cv[(size_t)b * 40 + lane] = s * 0.02f;
    }
}

// ===================== k_tail =====================
__global__ __launch_bounds__(256) void k_tail(
    const float* __restrict__ protein, const float* __restrict__ b2,
    const float* __restrict__ W3, const float* __restrict__ b3,
    const float* __restrict__ Wp, const float* __restrict__ bp,
    const float* __restrict__ Watt, const float* __restrict__ batt,
    const float* __restrict__ Wm, const float* __restrict__ bm,
    const float* __restrict__ Wo, const float* __restrict__ bo,
    const float* __restrict__ ws_cv, const float* __restrict__ ws_part,
    float* __restrict__ out)
{
    const int G = 8, PC = 520;
    __shared__ float pc[8 * 520];    // [a256(256) | p256(256)] per sample
    __shared__ float p40s[8 * 40];
    __shared__ float phs[8 * 40];
    __shared__ float wts[8];
    __shared__ float cps[2][8 * 84];
    const int tid  = threadIdx.x;
    const int lane = tid & 63, wv = tid >> 6;
    const int b0   = blockIdx.x * G;
    const int c0   = lane * 4;

    // a256 = sum_kc partials + b2 (thread owns col tid for all 8 samples)
    {
        const float b2v = b2[tid];
        #pragma unroll
        for (int g = 0; g < G; ++g) {
            float s = b2v;
            #pragma unroll
            for (int kc = 0; kc < 8; ++kc)
                s += ws_part[((size_t)kc * BATCH + b0 + g) * 256 + tid];
            pc[g * PC + tid] = s;
        }
    }
    // p256 in registers: wave handles samples wv*2, wv*2+1
    {
        float acc[2][4] = {{0.f,0.f,0.f,0.f},{0.f,0.f,0.f,0.f}};
        const float* prot = protein + (size_t)(b0 + wv * 2) * 512;
        for (int j4 = 0; j4 < 128; ++j4) {
            float pv0[4], pv1[4];
            *(float4*)pv0 = *(const float4*)(prot + j4 * 4);
            *(float4*)pv1 = *(const float4*)(prot + 512 + j4 * 4);
            #pragma unroll
            for (int u = 0; u < 4; ++u) {
                float w3v[4];
                *(float4*)w3v = *(const float4*)(W3 + (size_t)(j4 * 4 + u) * 256 + c0);
                #pragma unroll
                for (int c = 0; c < 4; ++c) {
                    acc[0][c] = fmaf(pv0[u], w3v[c], acc[0][c]);
                    acc[1][c] = fmaf(pv1[u], w3v[c], acc[1][c]);
                }
            }
        }
        float b3v[4];
        *(float4*)b3v = *(const float4*)(b3 + c0);
        #pragma unroll
        for (int s = 0; s < 2; ++s) {
            float o[4];
            #pragma unroll
            for (int c = 0; c < 4; ++c) o[c] = acc[s][c] + b3v[c];
            *(float4*)(pc + (wv * 2 + s) * PC + 256 + c0) = *(float4*)o;
        }
    }
    __syncthreads();

    // p40 = pcat @ Wp + bp (40 tasks: 5 f8-groups x 8 samples)
    if (tid < 40) {
        const int f8 = tid >> 3, g = tid & 7, fo = f8 * 8;
        float a8[8];
        #pragma unroll
        for (int c = 0; c < 8; ++c) a8[c] = bp[fo + c];
        for (int j4 = 0; j4 < 128; ++j4) {
            float pv[4];
            *(float4*)pv = *(float4*)(pc + g * PC + j4 * 4);
            #pragma unroll
            for (int u = 0; u < 4; ++u) {
                const int j = j4 * 4 + u;
                float wa[4], wb[4];
                *(float4*)wa = *(const float4*)(Wp + j * 40 + fo);
                *(float4*)wb = *(const float4*)(Wp + j * 40 + fo + 4);
                #pragma unroll
                for (int c = 0; c < 4; ++c) {
                    a8[c]     = fmaf(pv[u], wa[c], a8[c]);
                    a8[4 + c] = fmaf(pv[u], wb[c], a8[4 + c]);
                }
            }
        }
        *(float4*)(p40s + g * 40 + fo)     = *(float4*)a8;
        *(float4*)(p40s + g * 40 + fo + 4) = *(float4*)(a8 + 4);
    }
    __syncthreads();

    // protein_h = relu(p40 @ Watt + batt)
    for (int it = tid; it < G * 40; it += 256) {
        const int g = it / 40, f = it - g * 40;
        float s = batt[f];
        #pragma unroll
        for (int j4 = 0; j4 < 10; ++j4) {
            float pv[4];
            *(float4*)pv = *(float4*)(p40s + g * 40 + j4 * 4);
            #pragma unroll
            for (int u = 0; u < 4; ++u)
                s = fmaf(pv[u], Watt[(j4 * 4 + u) * 40 + f], s);
        }
        phs[it] = s > 0.f ? s : 0.f;
    }
    __syncthreads();

    if (tid < G) {
        float m = 0.f;
        #pragma unroll
        for (int f4 = 0; f4 < 10; ++f4) {
            float cv[4], ph[4];
            *(float4*)cv = *(const float4*)(ws_cv + (size_t)(b0 + tid) * 40 + f4 * 4);
            *(float4*)ph = *(float4*)(phs + tid * 40 + f4 * 4);
            #pragma unroll
            for (int c = 0; c < 4; ++c) m = fmaf(cv[c], ph[c], m);
        }
        wts[tid] = tanhf(m);
    }
    __syncthreads();

    for (int it = tid; it < G * 80; it += 256) {
        const int g = it / 80, f = it - g * 80;
        const float v = (f < 40) ? ws_cv[(size_t)(b0 + g) * 40 + f]
                                 : wts[g] * phs[g * 40 + (f - 40)];
        cps[0][g * 84 + f] = v;
    }
    __syncthreads();

    int cb = 0;
    for (int l = 0; l < 2; ++l) {
        for (int it = tid; it < G * 80; it += 256) {
            const int g = it / 80, kk = it - g * 80;
            float s = bm[l * 80 + kk];
            #pragma unroll
            for (int j4 = 0; j4 < 20; ++j4) {
                float cv[4];
                *(float4*)cv = *(float4*)(cps[cb] + g * 84 + j4 * 4);
                #pragma unroll
                for (int u = 0; u < 4; ++u)
                    s = fmaf(cv[u], Wm[l * 6400 + (j4 * 4 + u) * 80 + kk], s);
            }
            cps[cb ^ 1][g * 84 + kk] = s > 0.f ? s : 0.f;
        }
        __syncthreads();
        cb ^= 1;
    }
    if (tid < G) {
        float s = bo[0];
        #pragma unroll
        for (int j4 = 0; j4 < 20; ++j4) {
            float cv[4], wo[4];
            *(float4*)cv = *(float4*)(cps[cb] + tid * 84 + j4 * 4);
            *(float4*)wo = *(const float4*)(Wo + j4 * 4);
            #pragma unroll
            for (int u = 0; u < 4; ++u) s = fmaf(cv[u], wo[u], s);
        }
        out[b0 + tid] = s;
    }
}

extern "C" void kernel_launch(void* const* d_in, const int* in_sizes, int n_in,
                              void* d_out, int out_size, void* d_ws, size_t ws_size,
                              hipStream_t stream) {
    const int*   atoms   = (const int*)d_in[0];
    const float* A       = (const float*)d_in[1];
    const float* A69     = (const float*)d_in[2];
    const float* protein = (const float*)d_in[3];
    const float* emb     = (const float*)d_in[4];
    const float* Wg      = (const float*)d_in[5];
    const float* bg      = (const float*)d_in[6];
    const float* Watt    = (const float*)d_in[7];
    const float* batt    = (const float*)d_in[8];
    const float* W1      = (const float*)d_in[9];
    const float* b1      = (const float*)d_in[10];
    const float* W2      = (const float*)d_in[11];
    const float* b2      = (const float*)d_in[12];
    const float* W3      = (const float*)d_in[13];
    const float* b3      = (const float*)d_in[14];
    const float* Wp      = (const float*)d_in[15];
    const float* bp      = (const float*)d_in[16];
    const float* Wm      = (const float*)d_in[17];
    const float* bm      = (const float*)d_in[18];
    const float* Wo      = (const float*)d_in[19];
    const float* bo      = (const float*)d_in[20];

    float* ws_cv   = (float*)d_ws;                  // [4096][40]
    float* ws_part = ws_cv + (size_t)BATCH * 40;    // [8][4096][256]
    float* outp    = (float*)d_out;

    k_stream<<<dim3(4096), dim3(256), 0, stream>>>(A69, W1, b1, W2, ws_part);
    k_gnn<<<dim3(BATCH), dim3(64), 0, stream>>>(atoms, A, emb, Wg, bg, ws_cv);
    k_tail<<<dim3(512), dim3(256), 0, stream>>>(
        protein, b2, W3, b3, Wp, bp, Watt, batt, Wm, bm, Wo, bo,
        ws_cv, ws_part, outp);
}

// Round 8
// 365.048 us; speedup vs baseline: 1.3243x; 1.0137x over previous
//
#include <hip/hip_runtime.h>
#include <hip/hip_bf16.h>
#include <math.h>

// GanDTI forward. B=4096, N_ATOMS=50, FEAT=40, GNN_DEPTH=3, MLP_DEPTH=2.
//
//  k_stream (UNCHANGED round-7 control): 4096 blocks x 256 thr
//            = 512 sample-groups x 8 k-chunks -> partial a256.
//  k_gnn  (v2): 4096 blocks x 64 thr (one wave/sample, no barriers).
//            5x8 register tile; comp/h in LDS (17.6 KB -> ~8 blocks/CU);
//            Wg read from GLOBAL (L1-resident, off the LDS port); A from global.
//  k_tail (v2): 512 blocks x 256 thr, 8 samples/block, wave-specialized phase 0:
//            wv0/1 = p256 for 4 samples each (halves W3 L2 traffic),
//            wv2/3 = a256 partial-reduce concurrently. Then p40/attn/MLP.

#define BATCH 4096
#define SC 44   // comp/h row stride in k_gnn

// ===================== k_stream =====================
__global__ __launch_bounds__(256) void k_stream(
    const float* __restrict__ A69, const float* __restrict__ W1,
    const float* __restrict__ b1, const float* __restrict__ W2,
    float* __restrict__ ws_part)
{
    __shared__ float a69s[64 * 10];
    const int tid  = threadIdx.x;
    const int lane = tid & 63, wv = tid >> 6;
    const int kc = blockIdx.x & 7, sg = blockIdx.x >> 3;
    const int s0 = sg * 8, k0 = kc * 128;
    const int c0 = lane * 4;

    float w1r[30];
    #pragma unroll
    for (int k = 0; k < 15; ++k) {
        float2 t = ((const float2*)W1)[k];
        w1r[2 * k] = t.x; w1r[2 * k + 1] = t.y;
    }
    const float b1v = b1[0];

    float acc[2][4] = {{0.f,0.f,0.f,0.f},{0.f,0.f,0.f,0.f}};

    for (int h = 0; h < 2; ++h) {
        const int base = k0 + h * 64;
        const int nrh = (1001 - base < 64) ? (1001 - base) : 64;  // kc=7,h=1 -> 41
        if (h) __syncthreads();
        for (int idx = tid; idx < 512; idx += 256) {
            const int s = idx >> 6, rr = idx & 63;
            if (rr < nrh) {
                const float2* p = (const float2*)(A69 + ((size_t)(s0 + s) * 1001 + base + rr) * 30);
                float v = b1v;
                #pragma unroll
                for (int k = 0; k < 15; ++k) {
                    float2 q = p[k];
                    v = fmaf(q.x, w1r[2 * k], v);
                    v = fmaf(q.y, w1r[2 * k + 1], v);
                }
                a69s[rr * 10 + s] = v;
            }
        }
        __syncthreads();
        for (int k = 0; k < nrh; ++k) {
            const float a0 = a69s[k * 10 + wv * 2];       // wave-uniform broadcast
            const float a1 = a69s[k * 10 + wv * 2 + 1];
            float w2v[4];
            *(float4*)w2v = *(const float4*)(W2 + (size_t)(base + k) * 256 + c0);
            #pragma unroll
            for (int c = 0; c < 4; ++c) {
                acc[0][c] = fmaf(a0, w2v[c], acc[0][c]);
                acc[1][c] = fmaf(a1, w2v[c], acc[1][c]);
            }
        }
    }
    #pragma unroll
    for (int s = 0; s < 2; ++s)
        *(float4*)(ws_part + ((size_t)kc * BATCH + s0 + wv * 2 + s) * 256 + c0) = *(float4*)acc[s];
}

// ===================== k_gnn (v2) =====================
__global__ __launch_bounds__(64, 2) void k_gnn(
    const int* __restrict__ atoms, const float* __restrict__ A,
    const float* __restrict__ emb, const float* __restrict__ Wg,
    const float* __restrict__ bg, float* __restrict__ ws_cv)
{
    __shared__ float comp[50 * SC];
    __shared__ float h_s[50 * SC];
    const int lane = threadIdx.x;
    const int b = blockIdx.x;

    // stage comp = emb[atoms] (same-wave in-order LDS: no barriers needed)
    for (int i = lane; i < 500; i += 64) {
        const int n = i / 10, f4 = i - n * 10;
        const int row = atoms[b * 50 + n];
        *(float4*)(comp + n * SC + f4 * 4) = *(const float4*)(emb + row * 40 + f4 * 4);
    }

    const int rg = lane / 5;          // 0..9 (valid for lane<50)
    const int cg = lane - rg * 5;     // 0..4
    const int n0 = rg * 5, f0 = cg * 8;
    const bool act = (lane < 50);

    // residual partial over own 5 rows
    float res8[8] = {0,0,0,0,0,0,0,0};
    if (act) {
        #pragma unroll
        for (int k = 0; k < 5; ++k) {
            float cv[8];
            *(float4*)cv       = *(float4*)(comp + (n0 + k) * SC + f0);
            *(float4*)(cv + 4) = *(float4*)(comp + (n0 + k) * SC + f0 + 4);
            #pragma unroll
            for (int c = 0; c < 8; ++c) res8[c] += cv[c];
        }
    }

    const float* Ab = A + (size_t)b * 2500;

    for (int l = 0; l < 3; ++l) {
        const float* wgl = Wg + l * 1600;
        if (act) {
            // ---- m1: h = leaky(comp @ Wg[l] + bg[l]); Wg from global (L1) ----
            float bgv[8];
            *(float4*)bgv       = *(const float4*)(bg + l * 40 + f0);
            *(float4*)(bgv + 4) = *(const float4*)(bg + l * 40 + f0 + 4);
            float acc[5][8];
            #pragma unroll
            for (int k = 0; k < 5; ++k)
                #pragma unroll
                for (int c = 0; c < 8; ++c) acc[k][c] = bgv[c];
            #pragma unroll
            for (int j4 = 0; j4 < 10; ++j4) {
                float cv[5][4];
                #pragma unroll
                for (int k = 0; k < 5; ++k)
                    *(float4*)cv[k] = *(float4*)(comp + (n0 + k) * SC + j4 * 4);
                #pragma unroll
                for (int u = 0; u < 4; ++u) {
                    float w8[8];
                    *(float4*)w8       = *(const float4*)(wgl + (j4 * 4 + u) * 40 + f0);
                    *(float4*)(w8 + 4) = *(const float4*)(wgl + (j4 * 4 + u) * 40 + f0 + 4);
                    #pragma unroll
                    for (int k = 0; k < 5; ++k)
                        #pragma unroll
                        for (int c = 0; c < 8; ++c)
                            acc[k][c] = fmaf(cv[k][u], w8[c], acc[k][c]);
                }
            }
            #pragma unroll
            for (int k = 0; k < 5; ++k) {
                float hv[8];
                #pragma unroll
                for (int c = 0; c < 8; ++c) {
                    const float s = acc[k][c];
                    hv[c] = s > 0.f ? s : 0.01f * s;
                }
                *(float4*)(h_s + (n0 + k) * SC + f0)     = *(float4*)hv;
                *(float4*)(h_s + (n0 + k) * SC + f0 + 4) = *(float4*)(hv + 4);
            }
            // ---- m2: comp += A @ h (A from global, float2 = 8B-aligned) ----
            float acc2[5][8];
            #pragma unroll
            for (int k = 0; k < 5; ++k)
                #pragma unroll
                for (int c = 0; c < 8; ++c) acc2[k][c] = 0.f;
            #pragma unroll
            for (int m4 = 0; m4 < 12; ++m4) {
                float af[5][4];
                #pragma unroll
                for (int k = 0; k < 5; ++k) {
                    *(float2*)af[k]       = *(const float2*)(Ab + (n0 + k) * 50 + m4 * 4);
                    *(float2*)(af[k] + 2) = *(const float2*)(Ab + (n0 + k) * 50 + m4 * 4 + 2);
                }
                #pragma unroll
                for (int u = 0; u < 4; ++u) {
                    float h8[8];
                    *(float4*)h8       = *(float4*)(h_s + (m4 * 4 + u) * SC + f0);
                    *(float4*)(h8 + 4) = *(float4*)(h_s + (m4 * 4 + u) * SC + f0 + 4);
                    #pragma unroll
                    for (int k = 0; k < 5; ++k)
                        #pragma unroll
                        for (int c = 0; c < 8; ++c)
                            acc2[k][c] = fmaf(af[k][u], h8[c], acc2[k][c]);
                }
            }
            {   // tail m = 48, 49
                float h48[8], h49[8];
                *(float4*)h48       = *(float4*)(h_s + 48 * SC + f0);
                *(float4*)(h48 + 4) = *(float4*)(h_s + 48 * SC + f0 + 4);
                *(float4*)h49       = *(float4*)(h_s + 49 * SC + f0);
                *(float4*)(h49 + 4) = *(float4*)(h_s + 49 * SC + f0 + 4);
                #pragma unroll
                for (int k = 0; k < 5; ++k) {
                    const float a48 = Ab[(n0 + k) * 50 + 48];
                    const float a49 = Ab[(n0 + k) * 50 + 49];
                    #pragma unroll
                    for (int c = 0; c < 8; ++c) {
                        acc2[k][c] = fmaf(a48, h48[c], acc2[k][c]);
                        acc2[k][c] = fmaf(a49, h49[c], acc2[k][c]);
                    }
                }
            }
            #pragma unroll
            for (int k = 0; k < 5; ++k) {
                float cv[8];
                *(float4*)cv       = *(float4*)(comp + (n0 + k) * SC + f0);
                *(float4*)(cv + 4) = *(float4*)(comp + (n0 + k) * SC + f0 + 4);
                #pragma unroll
                for (int c = 0; c < 8; ++c) cv[c] += acc2[k][c];
                *(float4*)(comp + (n0 + k) * SC + f0)     = *(float4*)cv;
                *(float4*)(comp + (n0 + k) * SC + f0 + 4) = *(float4*)(cv + 4);
            }
        }
    }

    // mean over atoms + residual
    if (act) {
        float s8[8];
        #pragma unroll
        for (int c = 0; c < 8; ++c) s8[c] = res8[c];
        #pragma unroll
        for (int k = 0; k < 5; ++k) {
            float cv[8];
            *(float4*)cv       = *(float4*)(comp + (n0 + k) * SC + f0);
            *(float4*)(cv + 4) = *(float4*)(comp + (n0 + k) * SC + f0 + 4);
            #pragma unroll
            for (int c = 0; c < 8; ++c) s8[c] += cv[c];
        }
        *(float4*)(h_s + rg * 40 + f0)     = *(float4*)s8;
        *(float4*)(h_s + rg * 40 + f0 + 4) = *(float4*)(s8 + 4);
    }
    if (lane < 40) {
        float s = 0.f;
        #pragma unroll
        for (int r = 0; r < 10; ++r) s += h_s[r * 40 + lane];
        ws_cv[(size_t)b * 40 + lane] = s * 0.02f;
    }
}

// ===================== k_tail (v2) =====================
__global__ __launch_bounds__(256) void k_tail(
    const float* __restrict__ protein, const float* __restrict__ b2,
    const float* __restrict__ W3, const float* __restrict__ b3,
    const float* __restrict__ Wp, const float* __restrict__ bp,
    const float* __restrict__ Watt, const float* __restrict__ batt,
    const float* __restrict__ Wm, const float* __restrict__ bm,
    const float* __restrict__ Wo, const float* __restrict__ bo,
    const float* __restrict__ ws_cv, const float* __restrict__ ws_part,
    float* __restrict__ out)
{
    const int G = 8, PC = 520;
    __shared__ float pc[8 * 520];    // [a256(256) | p256(256)] per sample
    __shared__ float p40s[8 * 40];
    __shared__ float phs[8 * 40];
    __shared__ float wts[8];
    __shared__ float cps[2][8 * 84];
    const int tid  = threadIdx.x;
    const int lane = tid & 63, wv = tid >> 6;
    const int b0   = blockIdx.x * G;
    const int c0   = lane * 4;

    // ---- phase 0, wave-specialized ----
    if (wv < 2) {
        // p256 = protein @ W3 + b3 for samples wv*4 .. wv*4+3 (registers)
        float acc[4][4];
        #pragma unroll
        for (int s = 0; s < 4; ++s)
            #pragma unroll
            for (int c = 0; c < 4; ++c) acc[s][c] = 0.f;
        const float* prot = protein + (size_t)(b0 + wv * 4) * 512;
        for (int j4 = 0; j4 < 128; ++j4) {
            float pv[4][4];
            #pragma unroll
            for (int s = 0; s < 4; ++s)
                *(float4*)pv[s] = *(const float4*)(prot + (size_t)s * 512 + j4 * 4);
            #pragma unroll
            for (int u = 0; u < 4; ++u) {
                float w3v[4];
                *(float4*)w3v = *(const float4*)(W3 + (size_t)(j4 * 4 + u) * 256 + c0);
                #pragma unroll
                for (int s = 0; s < 4; ++s)
                    #pragma unroll
                    for (int c = 0; c < 4; ++c)
                        acc[s][c] = fmaf(pv[s][u], w3v[c], acc[s][c]);
            }
        }
        float b3v[4];
        *(float4*)b3v = *(const float4*)(b3 + c0);
        #pragma unroll
        for (int s = 0; s < 4; ++s) {
            float o[4];
            #pragma unroll
            for (int c = 0; c < 4; ++c) o[c] = acc[s][c] + b3v[c];
            *(float4*)(pc + (wv * 4 + s) * PC + 256 + c0) = *(float4*)o;
        }
    } else {
        // a256 = sum_kc partials + b2 for samples (wv-2)*4 .. +3
        const int sbase = (wv - 2) * 4;
        float b2v[4];
        *(float4*)b2v = *(const float4*)(b2 + c0);
        #pragma unroll
        for (int s = 0; s < 4; ++s) {
            float o[4] = {b2v[0], b2v[1], b2v[2], b2v[3]};
            #pragma unroll
            for (int kc = 0; kc < 8; ++kc) {
                float pv[4];
                *(float4*)pv = *(const float4*)(ws_part + ((size_t)kc * BATCH + b0 + sbase + s) * 256 + c0);
                #pragma unroll
                for (int c = 0; c < 4; ++c) o[c] += pv[c];
            }
            *(float4*)(pc + (sbase + s) * PC + c0) = *(float4*)o;
        }
    }
    __syncthreads();

    // ---- p40 = pcat @ Wp + bp (40 tasks: 5 f8-groups x 8 samples) ----
    if (tid < 40) {
        const int f8 = tid >> 3, g = tid & 7, fo = f8 * 8;
        float a8[8];
        #pragma unroll
        for (int c = 0; c < 8; ++c) a8[c] = bp[fo + c];
        for (int j4 = 0; j4 < 128; ++j4) {
            float pv[4];
            *(float4*)pv = *(float4*)(pc + g * PC + j4 * 4);
            #pragma unroll
            for (int u = 0; u < 4; ++u) {
                const int j = j4 * 4 + u;
                float wa[4], wb[4];
                *(float4*)wa = *(const float4*)(Wp + j * 40 + fo);
                *(float4*)wb = *(const float4*)(Wp + j * 40 + fo + 4);
                #pragma unroll
                for (int c = 0; c < 4; ++c) {
                    a8[c]     = fmaf(pv[u], wa[c], a8[c]);
                    a8[4 + c] = fmaf(pv[u], wb[c], a8[4 + c]);
                }
            }
        }
        *(float4*)(p40s + g * 40 + fo)     = *(float4*)a8;
        *(float4*)(p40s + g * 40 + fo + 4) = *(float4*)(a8 + 4);
    }
    __syncthreads();

    // ---- protein_h = relu(p40 @ Watt + batt) ----
    for (int it = tid; it < G * 40; it += 256) {
        const int g = it / 40, f = it - g * 40;
        float s = batt[f];
        #pragma unroll
        for (int j4 = 0; j4 < 10; ++j4) {
            float pv[4];
            *(float4*)pv = *(float4*)(p40s + g * 40 + j4 * 4);
            #pragma unroll
            for (int u = 0; u < 4; ++u)
                s = fmaf(pv[u], Watt[(j4 * 4 + u) * 40 + f], s);
        }
        phs[it] = s > 0.f ? s : 0.f;
    }
    __syncthreads();

    if (tid < G) {
        float m = 0.f;
        #pragma unroll
        for (int f4 = 0; f4 < 10; ++f4) {
            float cv[4], ph[4];
            *(float4*)cv = *(const float4*)(ws_cv + (size_t)(b0 + tid) * 40 + f4 * 4);
            *(float4*)ph = *(float4*)(phs + tid * 40 + f4 * 4);
            #pragma unroll
            for (int c = 0; c < 4; ++c) m = fmaf(cv[c], ph[c], m);
        }
        wts[tid] = tanhf(m);
    }
    __syncthreads();

    for (int it = tid; it < G * 80; it += 256) {
        const int g = it / 80, f = it - g * 80;
        const float v = (f < 40) ? ws_cv[(size_t)(b0 + g) * 40 + f]
                                 : wts[g] * phs[g * 40 + (f - 40)];
        cps[0][g * 84 + f] = v;
    }
    __syncthreads();

    int cb = 0;
    for (int l = 0; l < 2; ++l) {
        for (int it = tid; it < G * 80; it += 256) {
            const int g = it / 80, kk = it - g * 80;
            float s = bm[l * 80 + kk];
            #pragma unroll
            for (int j4 = 0; j4 < 20; ++j4) {
                float cv[4];
                *(float4*)cv = *(float4*)(cps[cb] + g * 84 + j4 * 4);
                #pragma unroll
                for (int u = 0; u < 4; ++u)
                    s = fmaf(cv[u], Wm[l * 6400 + (j4 * 4 + u) * 80 + kk], s);
            }
            cps[cb ^ 1][g * 84 + kk] = s > 0.f ? s : 0.f;
        }
        __syncthreads();
        cb ^= 1;
    }
    if (tid < G) {
        float s = bo[0];
        #pragma unroll
        for (int j4 = 0; j4 < 20; ++j4) {
            float cv[4], wo[4];
            *(float4*)cv = *(float4*)(cps[cb] + tid * 84 + j4 * 4);
            *(float4*)wo = *(const float4*)(Wo + j4 * 4);
            #pragma unroll
            for (int u = 0; u < 4; ++u) s = fmaf(cv[u], wo[u], s);
        }
        out[b0 + tid] = s;
    }
}

extern "C" void kernel_launch(void* const* d_in, const int* in_sizes, int n_in,
                              void* d_out, int out_size, void* d_ws, size_t ws_size,
                              hipStream_t stream) {
    const int*   atoms   = (const int*)d_in[0];
    const float* A       = (const float*)d_in[1];
    const float* A69     = (const float*)d_in[2];
    const float* protein = (const float*)d_in[3];
    const float* emb     = (const float*)d_in[4];
    const float* Wg      = (const float*)d_in[5];
    const float* bg      = (const float*)d_in[6];
    const float* Watt    = (const float*)d_in[7];
    const float* batt    = (const float*)d_in[8];
    const float* W1      = (const float*)d_in[9];
    const float* b1      = (const float*)d_in[10];
    const float* W2      = (const float*)d_in[11];
    const float* b2      = (const float*)d_in[12];
    const float* W3      = (const float*)d_in[13];
    const float* b3      = (const float*)d_in[14];
    const float* Wp      = (const float*)d_in[15];
    const float* bp      = (const float*)d_in[16];
    const float* Wm      = (const float*)d_in[17];
    const float* bm      = (const float*)d_in[18];
    const float* Wo      = (const float*)d_in[19];
    const float* bo      = (const float*)d_in[20];

    float* ws_cv   = (float*)d_ws;                  // [4096][40]
    float* ws_part = ws_cv + (size_t)BATCH * 40;    // [8][4096][256]
    float* outp    = (float*)d_out;

    k_stream<<<dim3(4096), dim3(256), 0, stream>>>(A69, W1, b1, W2, ws_part);
    k_gnn<<<dim3(BATCH), dim3(64), 0, stream>>>(atoms, A, emb, Wg, bg, ws_cv);
    k_tail<<<dim3(512), dim3(256), 0, stream>>>(
        protein, b2, W3, b3, Wp, bp, Watt, batt, Wm, bm, Wo, bo,
        ws_cv, ws_part, outp);
}